// Round 18
// baseline (169.411 us; speedup 1.0000x reference)
//
#include <hip/hip_runtime.h>

#define HH 512
#define WW 512
#define NPIX (HH*WW)
#define KK 16
#define BB 8
#define NB 192   // lovasz error histogram buckets (%64==0)
#define NBP 200  // padded LDS hist row (bank stagger)
#define CHV 128  // pixel chunks per image in k_hist (2048 px each)
// MEASUREMENT ROUND: k_sums body x5, k_hist body x4 (idempotent reps) to
// lift them above the ~40us poison-fill floor in the top-5 PMC table.
#define REP_SUMS 5
#define REP_HIST 4

__device__ __forceinline__ float fast_rcp(float x){ return __builtin_amdgcn_rcpf(x); }
__device__ __forceinline__ float fast_tanh(float x){
  x = fminf(fmaxf(x, -15.f), 15.f);
  float t = __expf(2.f*x);
  return (t-1.f)*fast_rcp(t+1.f);
}
__device__ __forceinline__ float fast_sigmoid(float x){
  x = fminf(fmaxf(x, -30.f), 30.f);
  return fast_rcp(1.f+__expf(-x));
}

__device__ __forceinline__ float dpp_row_sum16(float v){
  v += __int_as_float(__builtin_amdgcn_update_dpp(0, __float_as_int(v), 0x111, 0xf, 0xf, true));
  v += __int_as_float(__builtin_amdgcn_update_dpp(0, __float_as_int(v), 0x112, 0xf, 0xf, true));
  v += __int_as_float(__builtin_amdgcn_update_dpp(0, __float_as_int(v), 0x114, 0xf, 0xf, true));
  v += __int_as_float(__builtin_amdgcn_update_dpp(0, __float_as_int(v), 0x118, 0xf, 0xf, true));
  return v;
}

// ---------------- kernel 1: mask sums (5 comps) + bg seed, x5 reps --------
__global__ void __launch_bounds__(256) k_sums(
    const float* __restrict__ pred, const int* __restrict__ inst,
    const int* __restrict__ lab, float* __restrict__ partial_s /*[B][80][256]*/,
    float* __restrict__ partial_b /*[2048]*/) {
  const int bid = blockIdx.x;
  const int b  = bid & 7;
  const int ch = bid >> 3;
  const int tid = threadIdx.x;
  const int wave = tid >> 6, lane = tid & 63;
  __shared__ float lred[KK][16][5];
  __shared__ float lbg[4];
  const float inv = 1.f/511.f;
  const float* ps = pred + (size_t)b*4*NPIX + 2*NPIX;
  const float* pd = ps + NPIX;
  const int*   ib = inst + (size_t)b*NPIX;
  const int*   lb = lab  + (size_t)b*NPIX;

  for (int rep = 0; rep < REP_SUMS; ++rep) {
    int roff = 0;
    asm volatile("" : "+v"(roff));          // opaque 0: forces real re-loads
    const int p = ch*1024 + tid*4 + roff;
    int4   iv = *(const int4*)(ib + p);
    int4   lv = *(const int4*)(lb + p);
    float4 sv = *(const float4*)(ps + p);
    float4 dv = *(const float4*)(pd + p);
    const float ym  = (float)(p >> 9) * inv;
    const float xm0 = (float)(p & (WW-1)) * inv;
    int   ida[4] = {iv.x, iv.y, iv.z, iv.w};
    int   laa[4] = {lv.x, lv.y, lv.z, lv.w};
    float sga[4] = {sv.x, sv.y, sv.z, sv.w};
    float sda[4] = {dv.x, dv.y, dv.z, dv.w};
    float xja[4] = {xm0, xm0+inv, xm0+2.f*inv, xm0+3.f*inv};
    float sg2[4] = {sga[0]*sga[0], sga[1]*sga[1], sga[2]*sga[2], sga[3]*sga[3]};

    float sbg = 0.f;
    #pragma unroll
    for (int j = 0; j < 4; ++j)
      if (laa[j] == 0) { float sd = fast_sigmoid(sda[j]); sbg += sd*sd; }
    #pragma unroll
    for (int off = 32; off; off >>= 1) sbg += __shfl_down(sbg, off);
    if (lane == 0) lbg[wave] = sbg;

    #pragma unroll
    for (int k = 0; k < KK; ++k) {
      float c = 0.f, sx = 0.f, ss = 0.f, sq = 0.f;
      #pragma unroll
      for (int j = 0; j < 4; ++j) {
        float m = (ida[j] == k+1) ? 1.f : 0.f;
        c  += m;
        sx = fmaf(m, xja[j], sx);
        ss = fmaf(m, sga[j], ss);
        sq = fmaf(m, sg2[j], sq);
      }
      float sy = c * ym;
      c  = dpp_row_sum16(c);
      sx = dpp_row_sum16(sx);
      sy = dpp_row_sum16(sy);
      ss = dpp_row_sum16(ss);
      sq = dpp_row_sum16(sq);
      if ((lane & 15) == 15) {
        int g = wave*4 + (lane >> 4);
        lred[k][g][0] = c;  lred[k][g][1] = sx; lred[k][g][2] = sy;
        lred[k][g][3] = ss; lred[k][g][4] = sq;
      }
    }
    __syncthreads();
    if (tid < KK) {
      #pragma unroll
      for (int comp = 0; comp < 5; ++comp) {
        float a = 0.f;
        #pragma unroll
        for (int g = 0; g < 16; ++g) a += lred[tid][g][comp];
        partial_s[((size_t)b*80 + tid*5 + comp)*256 + ch] = a;
      }
    }
    if (tid == 64) partial_b[bid] = lbg[0] + lbg[1] + lbg[2] + lbg[3];
    __syncthreads();
  }
}

// ---------------- kernel 2: reduce partials -> der, seedbg ----------------
__global__ void __launch_bounds__(256) k_reduce(
    const float* __restrict__ partial_s, const float* __restrict__ partial_b,
    float* __restrict__ seedbg, float* __restrict__ der) {
  const int b = blockIdx.x;
  const int tid = threadIdx.x;
  const int w = tid >> 6, l = tid & 63;
  __shared__ float lsum[80];
  __shared__ float lsb[4];
  #pragma unroll
  for (int i = 0; i < 20; ++i) {
    int s = w + 4*i;
    const float* row = partial_s + ((size_t)b*80 + s)*256;
    float a = row[l] + row[l+64] + row[l+128] + row[l+192];
    #pragma unroll
    for (int off = 32; off; off >>= 1) a += __shfl_down(a, off);
    if (l == 0) lsum[s] = a;
  }
  {
    float a = partial_b[(size_t)tid*8 + b];
    #pragma unroll
    for (int off = 32; off; off >>= 1) a += __shfl_down(a, off);
    if (l == 0) lsb[w] = a;
  }
  __syncthreads();
  if (tid == 64) seedbg[b] = lsb[0] + lsb[1] + lsb[2] + lsb[3];
  if (tid < KK) {
    float cnt  = lsum[tid*5+0];
    float safe = fmaxf(cnt, 1.f);
    float rs   = fast_rcp(safe);
    float cx = lsum[tid*5+1]*rs;
    float cy = lsum[tid*5+2]*rs;
    float sb = lsum[tid*5+3]*rs;
    float sq = lsum[tid*5+4];
    float* dd = der + (b*KK + tid)*8;
    dd[0] = cx; dd[1] = cy;
    dd[2] = __expf(10.f*sb);
    dd[3] = (cnt > 0.f) ? 1.f : 0.f;
    dd[4] = sb;
    dd[5] = cnt;
    dd[6] = sq - cnt*sb*sb;
  }
}

// ---------------- kernel 3: unified 16-instance hist + fg seed, x4 reps ---
__global__ void __launch_bounds__(256, 4) k_hist(
    const float* __restrict__ pred, const int* __restrict__ inst,
    const float* __restrict__ der, unsigned int* __restrict__ hist,
    float* __restrict__ partial_v /*[1024]*/) {
  const int bid = blockIdx.x;
  const int b  = bid & 7;
  const int ch = bid >> 3;
  const int tid = threadIdx.x;
  const int g = tid >> 4, l4 = tid & 15;
  __shared__ unsigned int lh[KK][NBP];
  __shared__ float sder[KK][4];
  __shared__ float lsl[4];
  if (tid < KK) {
    const float* dd = der + (b*KK + tid)*8;
    sder[tid][0] = dd[0]; sder[tid][1] = dd[1];
    sder[tid][2] = dd[2]; sder[tid][3] = dd[3];
  }
  __syncthreads();
  float cxa[KK], cya[KK], sea[KK]; bool aca[KK];
  #pragma unroll
  for (int k = 0; k < KK; ++k) {
    cxa[k] = sder[k][0]; cya[k] = sder[k][1];
    sea[k] = sder[k][2]; aca[k] = sder[k][3] > 0.f;
  }
  const float inv = 1.f/511.f;
  const float* pbx = pred + (size_t)b*4*NPIX;
  const float* pby = pbx + NPIX;
  const float* pbd = pbx + 3*NPIX;
  const int*   ib  = inst + (size_t)b*NPIX;

  for (int rep = 0; rep < REP_HIST; ++rep) {
    for (int i = tid; i < KK*NBP; i += 256) ((unsigned int*)lh)[i] = 0u;
    __syncthreads();
    int roff = 0;
    asm volatile("" : "+v"(roff));          // opaque 0: forces real re-loads
    const int base = ch*2048 + g*128 + roff;
    float sloss = 0.f;
    #pragma unroll
    for (int it = 0; it < 2; ++it) {
      const int p = base + it*64 + l4*4;
      float4 px = *(const float4*)(pbx + p);
      float4 py = *(const float4*)(pby + p);
      int4   iv = *(const int4*)(ib + p);
      float4 dv = *(const float4*)(pbd + p);
      const float ym  = (float)(p >> 9) * inv;
      const float xm0 = (float)(p & (WW-1)) * inv;
      float pxa[4] = {px.x, px.y, px.z, px.w};
      float pya[4] = {py.x, py.y, py.z, py.w};
      int   ida[4] = {iv.x, iv.y, iv.z, iv.w};
      float sda[4] = {dv.x, dv.y, dv.z, dv.w};
      #pragma unroll
      for (int j = 0; j < 4; ++j) {
        float sex = fast_tanh(pxa[j]) + xm0 + (float)j*inv;
        float sey = fast_tanh(pya[j]) + ym;
        int id = ida[j];
        float down = 0.f;
        #pragma unroll
        for (int k = 0; k < KK; ++k) {
          if (aca[k]) {
            float dx = sex - cxa[k], dy = sey - cya[k];
            float d = __expf(-sea[k]*(dx*dx + dy*dy));
            bool fg = (id == k+1);
            float u  = fg ? (1.f - d) : d;
            int bkt = (int)(u * (float)NB);
            bkt = bkt < (NB-1) ? bkt : (NB-1);
            atomicAdd(&lh[k][bkt], fg ? 0x10001u : 1u);
            down = fg ? d : down;
          }
        }
        if (id >= 1) {
          float dsee = fast_sigmoid(sda[j]) - down;
          sloss = fmaf(dsee, dsee, sloss);
        }
      }
    }
    __syncthreads();
    #pragma unroll
    for (int k = 0; k < KK; ++k) {
      unsigned int* gh = hist + ((size_t)(b*KK + k)*CHV + ch)*NB;
      if (tid < NB) gh[tid] = lh[k][tid];
    }
    #pragma unroll
    for (int off = 32; off; off >>= 1) sloss += __shfl_down(sloss, off);
    if ((tid & 63) == 0) lsl[tid >> 6] = sloss;
    __syncthreads();
    if (tid == 0) partial_v[bid] = lsl[0] + lsl[1] + lsl[2] + lsl[3];
    __syncthreads();
  }
}

// ---------------- kernel 4: lovasz, 2-phase (collapse + scan) -------------
__global__ void __launch_bounds__(256) k_lovasz(
    const unsigned int* __restrict__ hist,
    const float* __restrict__ der, float* __restrict__ instl) {
  const int seg = blockIdx.x;
  const int tid = threadIdx.x;
  __shared__ float nbL[NB], fbL[NB];
  const float gts = der[seg*8 + 5];
  const unsigned int* h = hist + (size_t)seg*CHV*NB;
  if (tid < NB) {
    unsigned int nlo = 0, nhi = 0;
    #pragma unroll 8
    for (int c = 0; c < CHV; ++c) {
      unsigned int v = h[(size_t)c*NB + tid];
      nlo += v & 0xffffu; nhi += v >> 16;
    }
    nbL[tid] = (float)nlo; fbL[tid] = (float)nhi;
  }
  __syncthreads();
  if (tid >= 64) return;
  const int lane = tid;
  if (gts <= 0.f) { if (lane == 0) instl[seg] = 0.f; return; }
  float carryN = 0.f, carryF = 0.f, lsum = 0.f;
  #pragma unroll
  for (int it = 0; it < NB/64; ++it) {
    int bkt = NB - 1 - (it*64 + lane);
    float nb = nbL[bkt], fb = fbL[bkt];
    float sn = nb, sf = fb;
    #pragma unroll
    for (int off = 1; off < 64; off <<= 1) {
      float tn = __shfl_up(sn, off);
      float tf = __shfl_up(sf, off);
      if (lane >= off) { sn += tn; sf += tf; }
    }
    float Nb = carryN + sn - nb;
    float Fb = carryF + sf - fb;
    if (nb > 0.f) {
      float e  = ((float)bkt + 0.5f) * (2.0f/(float)NB);
      float j0 = 1.f - (gts - Fb) / (gts + Nb - Fb);
      float N1 = Nb + nb, F1 = Fb + fb;
      float j1 = 1.f - (gts - F1) / (gts + N1 - F1);
      lsum += e * (j1 - j0);
    }
    carryN += __shfl(sn, 63);
    carryF += __shfl(sf, 63);
  }
  #pragma unroll
  for (int off = 32; off; off >>= 1) lsum += __shfl_down(lsum, off);
  if (lane == 0) instl[seg] = lsum;
}

// ---------------- kernel 5: combine ---------------------------------------
__global__ void __launch_bounds__(256) k_final(
    const float* __restrict__ partial_v, const float* __restrict__ der,
    const float* __restrict__ instl, const float* __restrict__ seedbg,
    float* __restrict__ out) {
  __shared__ float vtmp[256];
  const int tid = threadIdx.x;
  {
    const int b8 = tid >> 5, j = tid & 31;
    float a = 0.f;
    #pragma unroll
    for (int i = 0; i < 4; ++i) a += partial_v[(size_t)(j + 32*i)*8 + b8];
    vtmp[tid] = a;
  }
  __syncthreads();
  float myv = 0.f;
  if (tid < BB) {
    int b = tid;
    float svl = 0.f;
    #pragma unroll
    for (int j = 0; j < 32; ++j) svl += vtmp[b*32 + j];
    float obj = 0.f, il = 0.f, vr = 0.f;
    for (int k = 0; k < KK; ++k) {
      int seg = b*KK + k;
      float cnt = der[seg*8 + 5];
      if (cnt > 0.f) {
        obj += 1.f;
        il  += instl[seg];
        vr  += der[seg*8 + 6] / cnt;
      }
    }
    float so = fmaxf(obj, 1.f);
    myv = il/so + 10.f*vr/so + (seedbg[b] + svl)/(float)NPIX;
  }
  #pragma unroll
  for (int off = 4; off; off >>= 1) myv += __shfl_down(myv, off);
  if (tid == 0) out[0] = myv * (1.f/(float)BB);
}

extern "C" void kernel_launch(void* const* d_in, const int* in_sizes, int n_in,
                              void* d_out, int out_size, void* d_ws, size_t ws_size,
                              hipStream_t stream) {
  const float* pred = (const float*)d_in[0];
  const int*   inst = (const int*)d_in[1];
  const int*   lab  = (const int*)d_in[2];
  float* out = (float*)d_out;

  float* der       = (float*)d_ws;
  float* seedbg    = (float*)((char*)d_ws + 4096);
  float* instl     = (float*)((char*)d_ws + 4160);
  float* partial_b = (float*)((char*)d_ws + 8192);
  float* partial_v = (float*)((char*)d_ws + 16384);
  float* partial_s = (float*)((char*)d_ws + 24576);
  unsigned int* hist = (unsigned int*)((char*)d_ws + 679936);

  k_sums  <<<BB*256, 256, 0, stream>>>(pred, inst, lab, partial_s, partial_b);
  k_reduce<<<BB, 256, 0, stream>>>(partial_s, partial_b, seedbg, der);
  k_hist  <<<BB*CHV, 256, 0, stream>>>(pred, inst, der, hist, partial_v);
  k_lovasz<<<BB*KK, 256, 0, stream>>>(hist, der, instl);
  k_final <<<1, 256, 0, stream>>>(partial_v, der, instl, seedbg, out);
}

// Round 19
// 123.756 us; speedup vs baseline: 1.3689x; 1.3689x over previous
//
#include <hip/hip_runtime.h>

#define HH 512
#define WW 512
#define NPIX (HH*WW)
#define KK 16
#define BB 8
#define NB 192   // lovasz error histogram buckets (%64==0)
#define NBP 200  // padded LDS hist row (bank stagger)
#define CHV 256  // pixel chunks per image in k_hist (1024 px each)

__device__ __forceinline__ float fast_rcp(float x){ return __builtin_amdgcn_rcpf(x); }
__device__ __forceinline__ float fast_tanh(float x){
  x = fminf(fmaxf(x, -15.f), 15.f);
  float t = __expf(2.f*x);
  return (t-1.f)*fast_rcp(t+1.f);
}
__device__ __forceinline__ float fast_sigmoid(float x){
  x = fminf(fmaxf(x, -30.f), 30.f);
  return fast_rcp(1.f+__expf(-x));
}

__device__ __forceinline__ float dpp_row_sum16(float v){
  v += __int_as_float(__builtin_amdgcn_update_dpp(0, __float_as_int(v), 0x111, 0xf, 0xf, true));
  v += __int_as_float(__builtin_amdgcn_update_dpp(0, __float_as_int(v), 0x112, 0xf, 0xf, true));
  v += __int_as_float(__builtin_amdgcn_update_dpp(0, __float_as_int(v), 0x114, 0xf, 0xf, true));
  v += __int_as_float(__builtin_amdgcn_update_dpp(0, __float_as_int(v), 0x118, 0xf, 0xf, true));
  return v;
}

// ---------------- kernel 1: mask sums (5 comps) + bg seed ------------------
// grid 2048: b = bid&7 (XCD-affine), ch = bid>>3; 1024 px/block, 4 px/lane.
__global__ void __launch_bounds__(256) k_sums(
    const float* __restrict__ pred, const int* __restrict__ inst,
    const int* __restrict__ lab, float* __restrict__ partial_s /*[B][80][256]*/,
    float* __restrict__ partial_b /*[2048]*/) {
  const int bid = blockIdx.x;
  const int b  = bid & 7;
  const int ch = bid >> 3;
  const int tid = threadIdx.x;
  const int wave = tid >> 6, lane = tid & 63;
  __shared__ float lred[KK][16][5];
  __shared__ float lbg[4];
  const float inv = 1.f/511.f;
  const float* ps = pred + (size_t)b*4*NPIX + 2*NPIX;
  const float* pd = ps + NPIX;
  const int*   ib = inst + (size_t)b*NPIX;
  const int*   lb = lab  + (size_t)b*NPIX;
  const int p = ch*1024 + tid*4;
  int4   iv = *(const int4*)(ib + p);
  int4   lv = *(const int4*)(lb + p);
  float4 sv = *(const float4*)(ps + p);
  float4 dv = *(const float4*)(pd + p);
  const float ym  = (float)(p >> 9) * inv;
  const float xm0 = (float)(p & (WW-1)) * inv;
  int   ida[4] = {iv.x, iv.y, iv.z, iv.w};
  int   laa[4] = {lv.x, lv.y, lv.z, lv.w};
  float sga[4] = {sv.x, sv.y, sv.z, sv.w};
  float sda[4] = {dv.x, dv.y, dv.z, dv.w};
  float xja[4] = {xm0, xm0+inv, xm0+2.f*inv, xm0+3.f*inv};
  float sg2[4] = {sga[0]*sga[0], sga[1]*sga[1], sga[2]*sga[2], sga[3]*sga[3]};

  float sbg = 0.f;
  #pragma unroll
  for (int j = 0; j < 4; ++j)
    if (laa[j] == 0) { float sd = fast_sigmoid(sda[j]); sbg += sd*sd; }
  #pragma unroll
  for (int off = 32; off; off >>= 1) sbg += __shfl_down(sbg, off);
  if (lane == 0) lbg[wave] = sbg;

  #pragma unroll
  for (int k = 0; k < KK; ++k) {
    float c = 0.f, sx = 0.f, ss = 0.f, sq = 0.f;
    #pragma unroll
    for (int j = 0; j < 4; ++j) {
      float m = (ida[j] == k+1) ? 1.f : 0.f;
      c  += m;
      sx = fmaf(m, xja[j], sx);
      ss = fmaf(m, sga[j], ss);
      sq = fmaf(m, sg2[j], sq);
    }
    float sy = c * ym;
    c  = dpp_row_sum16(c);
    sx = dpp_row_sum16(sx);
    sy = dpp_row_sum16(sy);
    ss = dpp_row_sum16(ss);
    sq = dpp_row_sum16(sq);
    if ((lane & 15) == 15) {
      int g = wave*4 + (lane >> 4);
      lred[k][g][0] = c;  lred[k][g][1] = sx; lred[k][g][2] = sy;
      lred[k][g][3] = ss; lred[k][g][4] = sq;
    }
  }
  __syncthreads();
  if (tid < KK) {
    #pragma unroll
    for (int comp = 0; comp < 5; ++comp) {
      float a = 0.f;
      #pragma unroll
      for (int g = 0; g < 16; ++g) a += lred[tid][g][comp];
      partial_s[((size_t)b*80 + tid*5 + comp)*256 + ch] = a;
    }
  }
  if (tid == 64) partial_b[bid] = lbg[0] + lbg[1] + lbg[2] + lbg[3];
}

// ---------------- kernel 2: reduce partials -> der (grid 128, 1/seg) ------
// der[seg][8] = {cx, cy, sexp, act, sbar, cnt, var, pad}
__global__ void __launch_bounds__(256) k_reduce(
    const float* __restrict__ partial_s, float* __restrict__ der) {
  const int seg = blockIdx.x;           // b*16 + k
  const int b = seg >> 4, k = seg & 15;
  const int tid = threadIdx.x;
  const int w = tid >> 6, l = tid & 63;
  __shared__ float red5[5][4];
  #pragma unroll
  for (int comp = 0; comp < 5; ++comp) {
    const float* row = partial_s + ((size_t)b*80 + k*5 + comp)*256;
    float a = row[tid];
    #pragma unroll
    for (int off = 32; off; off >>= 1) a += __shfl_down(a, off);
    if (l == 0) red5[comp][w] = a;
  }
  __syncthreads();
  if (tid == 0) {
    float cnt = red5[0][0]+red5[0][1]+red5[0][2]+red5[0][3];
    float sx  = red5[1][0]+red5[1][1]+red5[1][2]+red5[1][3];
    float sy  = red5[2][0]+red5[2][1]+red5[2][2]+red5[2][3];
    float ss  = red5[3][0]+red5[3][1]+red5[3][2]+red5[3][3];
    float sq  = red5[4][0]+red5[4][1]+red5[4][2]+red5[4][3];
    float safe = fmaxf(cnt, 1.f);
    float rs = fast_rcp(safe);
    float sb = ss*rs;
    float* dd = der + seg*8;
    dd[0] = sx*rs; dd[1] = sy*rs;
    dd[2] = __expf(10.f*sb);
    dd[3] = (cnt > 0.f) ? 1.f : 0.f;
    dd[4] = sb;
    dd[5] = cnt;
    dd[6] = sq - cnt*sb*sb;      // Σ(σ−s̄)² over mask
  }
}

// ---------------- kernel 3: unified 16-instance hist + fg seed loss -------
// grid 2048: b = bid&7, ch = bid>>3 in [0,256); 1024 px/block, 8 blocks/CU.
// BRANCHLESS: all 16 k histogrammed unconditionally (inactive-k rows are
// ignored downstream: k_lovasz returns 0 for gts<=0; fg can't hit inactive k).
__global__ void __launch_bounds__(256, 8) k_hist(
    const float* __restrict__ pred, const int* __restrict__ inst,
    const float* __restrict__ der, unsigned int* __restrict__ hist,
    float* __restrict__ partial_v /*[2048]*/) {
  const int bid = blockIdx.x;
  const int b  = bid & 7;
  const int ch = bid >> 3;
  const int tid = threadIdx.x;
  const int g = tid >> 4, l4 = tid & 15;   // 16 groups x 16 lanes
  __shared__ unsigned int lh[KK][NBP];
  __shared__ float sder[KK][4];
  __shared__ float lsl[4];
  if (tid < KK) {
    const float* dd = der + (b*KK + tid)*8;
    sder[tid][0] = dd[0]; sder[tid][1] = dd[1]; sder[tid][2] = dd[2];
  }
  for (int i = tid; i < KK*NBP; i += 256) ((unsigned int*)lh)[i] = 0u;
  __syncthreads();
  float cxa[KK], cya[KK], sea[KK];
  #pragma unroll
  for (int k = 0; k < KK; ++k) {
    cxa[k] = sder[k][0]; cya[k] = sder[k][1]; sea[k] = sder[k][2];
  }
  const float inv = 1.f/511.f;
  const float* pbx = pred + (size_t)b*4*NPIX;
  const float* pby = pbx + NPIX;
  const float* pbd = pbx + 3*NPIX;
  const int*   ib  = inst + (size_t)b*NPIX;
  const int p = ch*1024 + g*64 + l4*4;     // decorrelated group chunks
  float4 px = *(const float4*)(pbx + p);
  float4 py = *(const float4*)(pby + p);
  int4   iv = *(const int4*)(ib + p);
  float4 dv = *(const float4*)(pbd + p);
  const float ym  = (float)(p >> 9) * inv;
  const float xm0 = (float)(p & (WW-1)) * inv;
  float pxa[4] = {px.x, px.y, px.z, px.w};
  float pya[4] = {py.x, py.y, py.z, py.w};
  int   ida[4] = {iv.x, iv.y, iv.z, iv.w};
  float sda[4] = {dv.x, dv.y, dv.z, dv.w};
  float sloss = 0.f;
  #pragma unroll
  for (int j = 0; j < 4; ++j) {
    float sex = fast_tanh(pxa[j]) + xm0 + (float)j*inv;
    float sey = fast_tanh(pya[j]) + ym;
    int id = ida[j];
    float down = 0.f;
    #pragma unroll
    for (int k = 0; k < KK; ++k) {
      float dx = sex - cxa[k], dy = sey - cya[k];
      float d = __expf(-sea[k]*(dx*dx + dy*dy));
      bool fg = (id == k+1);
      float u  = fg ? (1.f - d) : d;
      int bkt = (int)(u * (float)NB);
      bkt = bkt < (NB-1) ? bkt : (NB-1);
      atomicAdd(&lh[k][bkt], fg ? 0x10001u : 1u);
      down = fg ? d : down;
    }
    if (id >= 1) {
      float dsee = fast_sigmoid(sda[j]) - down;
      sloss = fmaf(dsee, dsee, sloss);
    }
  }
  __syncthreads();
  #pragma unroll
  for (int k = 0; k < KK; ++k) {
    unsigned int* gh = hist + ((size_t)(b*KK + k)*CHV + ch)*NB;
    if (tid < NB) gh[tid] = lh[k][tid];
  }
  #pragma unroll
  for (int off = 32; off; off >>= 1) sloss += __shfl_down(sloss, off);
  if ((tid & 63) == 0) lsl[tid >> 6] = sloss;
  __syncthreads();
  if (tid == 0) partial_v[bid] = lsl[0] + lsl[1] + lsl[2] + lsl[3];
}

// ---------------- kernel 4: lovasz, 2-phase (collapse + scan) -------------
__global__ void __launch_bounds__(256) k_lovasz(
    const unsigned int* __restrict__ hist,
    const float* __restrict__ der, float* __restrict__ instl) {
  const int seg = blockIdx.x;
  const int tid = threadIdx.x;
  __shared__ float nbL[NB], fbL[NB];
  const float gts = der[seg*8 + 5];
  const unsigned int* h = hist + (size_t)seg*CHV*NB;
  if (tid < NB) {
    unsigned int nlo = 0, nhi = 0;
    #pragma unroll 8
    for (int c = 0; c < CHV; ++c) {
      unsigned int v = h[(size_t)c*NB + tid];
      nlo += v & 0xffffu; nhi += v >> 16;
    }
    nbL[tid] = (float)nlo; fbL[tid] = (float)nhi;
  }
  __syncthreads();
  if (tid >= 64) return;
  const int lane = tid;
  if (gts <= 0.f) { if (lane == 0) instl[seg] = 0.f; return; }
  float carryN = 0.f, carryF = 0.f, lsum = 0.f;
  #pragma unroll
  for (int it = 0; it < NB/64; ++it) {
    int bkt = NB - 1 - (it*64 + lane);
    float nb = nbL[bkt], fb = fbL[bkt];
    float sn = nb, sf = fb;
    #pragma unroll
    for (int off = 1; off < 64; off <<= 1) {
      float tn = __shfl_up(sn, off);
      float tf = __shfl_up(sf, off);
      if (lane >= off) { sn += tn; sf += tf; }
    }
    float Nb = carryN + sn - nb;
    float Fb = carryF + sf - fb;
    if (nb > 0.f) {
      float e  = ((float)bkt + 0.5f) * (2.0f/(float)NB);
      float j0 = 1.f - (gts - Fb) / (gts + Nb - Fb);
      float N1 = Nb + nb, F1 = Fb + fb;
      float j1 = 1.f - (gts - F1) / (gts + N1 - F1);
      lsum += e * (j1 - j0);
    }
    carryN += __shfl(sn, 63);
    carryF += __shfl(sf, 63);
  }
  #pragma unroll
  for (int off = 32; off; off >>= 1) lsum += __shfl_down(lsum, off);
  if (lane == 0) instl[seg] = lsum;
}

// ---------------- kernel 5: combine (also folds partial_b -> seedbg) ------
__global__ void __launch_bounds__(256) k_final(
    const float* __restrict__ partial_v, const float* __restrict__ partial_b,
    const float* __restrict__ der, const float* __restrict__ instl,
    float* __restrict__ out) {
  __shared__ float vtmp[256], btmp[256];
  const int tid = threadIdx.x;
  {
    const int b8 = tid >> 5, j = tid & 31;
    float a = 0.f, c = 0.f;
    #pragma unroll
    for (int i = 0; i < 8; ++i) {
      a += partial_v[(size_t)(j + 32*i)*8 + b8];
      c += partial_b[(size_t)(j + 32*i)*8 + b8];
    }
    vtmp[tid] = a; btmp[tid] = c;
  }
  __syncthreads();
  float myv = 0.f;
  if (tid < BB) {
    int b = tid;
    float svl = 0.f, sbg = 0.f;
    #pragma unroll
    for (int j = 0; j < 32; ++j) { svl += vtmp[b*32 + j]; sbg += btmp[b*32 + j]; }
    float obj = 0.f, il = 0.f, vr = 0.f;
    for (int k = 0; k < KK; ++k) {
      int seg = b*KK + k;
      float cnt = der[seg*8 + 5];
      if (cnt > 0.f) {
        obj += 1.f;
        il  += instl[seg];
        vr  += der[seg*8 + 6] / cnt;   // var/(N_SIGMA*safe), safe==cnt
      }
    }
    float so = fmaxf(obj, 1.f);
    myv = il/so + 10.f*vr/so + (sbg + svl)/(float)NPIX;
  }
  #pragma unroll
  for (int off = 4; off; off >>= 1) myv += __shfl_down(myv, off);
  if (tid == 0) out[0] = myv * (1.f/(float)BB);
}

extern "C" void kernel_launch(void* const* d_in, const int* in_sizes, int n_in,
                              void* d_out, int out_size, void* d_ws, size_t ws_size,
                              hipStream_t stream) {
  const float* pred = (const float*)d_in[0];
  const int*   inst = (const int*)d_in[1];
  const int*   lab  = (const int*)d_in[2];
  float* out = (float*)d_out;

  // ws layout (~26 MB of 256 MiB); all regions fully overwritten every call.
  float* der       = (float*)d_ws;                         // 128*8 f32
  float* instl     = (float*)((char*)d_ws + 4160);         // 128 f32
  float* partial_b = (float*)((char*)d_ws + 8192);         // 2048 f32
  float* partial_v = (float*)((char*)d_ws + 16384);        // 2048 f32
  float* partial_s = (float*)((char*)d_ws + 24576);        // 8*80*256 f32
  unsigned int* hist = (unsigned int*)((char*)d_ws + 679936); // 128*256*192*4 = 25.2MB

  k_sums  <<<BB*256, 256, 0, stream>>>(pred, inst, lab, partial_s, partial_b);
  k_reduce<<<BB*KK, 256, 0, stream>>>(partial_s, der);
  k_hist  <<<BB*CHV, 256, 0, stream>>>(pred, inst, der, hist, partial_v);
  k_lovasz<<<BB*KK, 256, 0, stream>>>(hist, der, instl);
  k_final <<<1, 256, 0, stream>>>(partial_v, partial_b, der, instl, out);
}

// Round 20
// 65.484 us; speedup vs baseline: 2.5871x; 1.8899x over previous
//
#include <hip/hip_runtime.h>

#define HH 512
#define WW 512
#define NPIX (HH*WW)
#define KK 16
#define BB 8
#define NB 192   // lovasz error histogram buckets (%64==0)
#define NBP 200  // padded LDS hist row (bank stagger)
#define CHV 128  // pixel chunks per image in k_hist (2048 px each)

__device__ __forceinline__ float fast_rcp(float x){ return __builtin_amdgcn_rcpf(x); }
__device__ __forceinline__ float fast_tanh(float x){
  x = fminf(fmaxf(x, -15.f), 15.f);
  float t = __expf(2.f*x);
  return (t-1.f)*fast_rcp(t+1.f);
}
__device__ __forceinline__ float fast_sigmoid(float x){
  x = fminf(fmaxf(x, -30.f), 30.f);
  return fast_rcp(1.f+__expf(-x));
}

__device__ __forceinline__ float dpp_row_sum16(float v){
  v += __int_as_float(__builtin_amdgcn_update_dpp(0, __float_as_int(v), 0x111, 0xf, 0xf, true));
  v += __int_as_float(__builtin_amdgcn_update_dpp(0, __float_as_int(v), 0x112, 0xf, 0xf, true));
  v += __int_as_float(__builtin_amdgcn_update_dpp(0, __float_as_int(v), 0x114, 0xf, 0xf, true));
  v += __int_as_float(__builtin_amdgcn_update_dpp(0, __float_as_int(v), 0x118, 0xf, 0xf, true));
  return v;
}

// ---------------- kernel 1: mask sums (5 comps) + bg seed ------------------
// grid 2048: b = bid&7 (XCD-affine), ch = bid>>3; 1024 px/block, 4 px/lane.
__global__ void __launch_bounds__(256) k_sums(
    const float* __restrict__ pred, const int* __restrict__ inst,
    const int* __restrict__ lab, float* __restrict__ partial_s /*[B][80][256]*/,
    float* __restrict__ partial_b /*[2048]*/) {
  const int bid = blockIdx.x;
  const int b  = bid & 7;
  const int ch = bid >> 3;
  const int tid = threadIdx.x;
  const int wave = tid >> 6, lane = tid & 63;
  __shared__ float lred[KK][16][5];
  __shared__ float lbg[4];
  const float inv = 1.f/511.f;
  const float* ps = pred + (size_t)b*4*NPIX + 2*NPIX;
  const float* pd = ps + NPIX;
  const int*   ib = inst + (size_t)b*NPIX;
  const int*   lb = lab  + (size_t)b*NPIX;
  const int p = ch*1024 + tid*4;
  int4   iv = *(const int4*)(ib + p);
  int4   lv = *(const int4*)(lb + p);
  float4 sv = *(const float4*)(ps + p);
  float4 dv = *(const float4*)(pd + p);
  const float ym  = (float)(p >> 9) * inv;
  const float xm0 = (float)(p & (WW-1)) * inv;
  int   ida[4] = {iv.x, iv.y, iv.z, iv.w};
  int   laa[4] = {lv.x, lv.y, lv.z, lv.w};
  float sga[4] = {sv.x, sv.y, sv.z, sv.w};
  float sda[4] = {dv.x, dv.y, dv.z, dv.w};
  float xja[4] = {xm0, xm0+inv, xm0+2.f*inv, xm0+3.f*inv};
  float sg2[4] = {sga[0]*sga[0], sga[1]*sga[1], sga[2]*sga[2], sga[3]*sga[3]};

  float sbg = 0.f;
  #pragma unroll
  for (int j = 0; j < 4; ++j)
    if (laa[j] == 0) { float sd = fast_sigmoid(sda[j]); sbg += sd*sd; }
  #pragma unroll
  for (int off = 32; off; off >>= 1) sbg += __shfl_down(sbg, off);
  if (lane == 0) lbg[wave] = sbg;

  #pragma unroll
  for (int k = 0; k < KK; ++k) {
    float c = 0.f, sx = 0.f, ss = 0.f, sq = 0.f;
    #pragma unroll
    for (int j = 0; j < 4; ++j) {
      float m = (ida[j] == k+1) ? 1.f : 0.f;
      c  += m;
      sx = fmaf(m, xja[j], sx);
      ss = fmaf(m, sga[j], ss);
      sq = fmaf(m, sg2[j], sq);
    }
    float sy = c * ym;
    c  = dpp_row_sum16(c);
    sx = dpp_row_sum16(sx);
    sy = dpp_row_sum16(sy);
    ss = dpp_row_sum16(ss);
    sq = dpp_row_sum16(sq);
    if ((lane & 15) == 15) {
      int g = wave*4 + (lane >> 4);
      lred[k][g][0] = c;  lred[k][g][1] = sx; lred[k][g][2] = sy;
      lred[k][g][3] = ss; lred[k][g][4] = sq;
    }
  }
  __syncthreads();
  if (tid < KK) {
    #pragma unroll
    for (int comp = 0; comp < 5; ++comp) {
      float a = 0.f;
      #pragma unroll
      for (int g = 0; g < 16; ++g) a += lred[tid][g][comp];
      partial_s[((size_t)b*80 + tid*5 + comp)*256 + ch] = a;
    }
  }
  if (tid == 64) partial_b[bid] = lbg[0] + lbg[1] + lbg[2] + lbg[3];
}

// ---------------- kernel 2: reduce partials -> der (grid 128, 1/seg) ------
// der[seg][8] = {cx, cy, sexp, act, sbar, cnt, var, pad}
__global__ void __launch_bounds__(256) k_reduce(
    const float* __restrict__ partial_s, float* __restrict__ der) {
  const int seg = blockIdx.x;           // b*16 + k
  const int b = seg >> 4, k = seg & 15;
  const int tid = threadIdx.x;
  const int w = tid >> 6, l = tid & 63;
  __shared__ float red5[5][4];
  #pragma unroll
  for (int comp = 0; comp < 5; ++comp) {
    const float* row = partial_s + ((size_t)b*80 + k*5 + comp)*256;
    float a = row[tid];
    #pragma unroll
    for (int off = 32; off; off >>= 1) a += __shfl_down(a, off);
    if (l == 0) red5[comp][w] = a;
  }
  __syncthreads();
  if (tid == 0) {
    float cnt = red5[0][0]+red5[0][1]+red5[0][2]+red5[0][3];
    float sx  = red5[1][0]+red5[1][1]+red5[1][2]+red5[1][3];
    float sy  = red5[2][0]+red5[2][1]+red5[2][2]+red5[2][3];
    float ss  = red5[3][0]+red5[3][1]+red5[3][2]+red5[3][3];
    float sq  = red5[4][0]+red5[4][1]+red5[4][2]+red5[4][3];
    float safe = fmaxf(cnt, 1.f);
    float rs = fast_rcp(safe);
    float sb = ss*rs;
    float* dd = der + seg*8;
    dd[0] = sx*rs; dd[1] = sy*rs;
    dd[2] = __expf(10.f*sb);
    dd[3] = (cnt > 0.f) ? 1.f : 0.f;
    dd[4] = sb;
    dd[5] = cnt;
    dd[6] = sq - cnt*sb*sb;      // Σ(σ−s̄)² over mask
  }
}

// ---------------- kernel 3: unified 16-instance hist + fg seed loss -------
// grid 1024: b = bid&7, ch = bid>>3 in [0,128); 2048 px/block, 4 blocks/CU
// (R18-proven geometry: VGPR 64, no spill). Branchless 16-k inner loop.
__global__ void __launch_bounds__(256, 4) k_hist(
    const float* __restrict__ pred, const int* __restrict__ inst,
    const float* __restrict__ der, unsigned int* __restrict__ hist,
    float* __restrict__ partial_v /*[1024]*/) {
  const int bid = blockIdx.x;
  const int b  = bid & 7;
  const int ch = bid >> 3;
  const int tid = threadIdx.x;
  const int g = tid >> 4, l4 = tid & 15;   // 16 groups x 16 lanes
  __shared__ unsigned int lh[KK][NBP];
  __shared__ float sder[KK][4];
  __shared__ float lsl[4];
  if (tid < KK) {
    const float* dd = der + (b*KK + tid)*8;
    sder[tid][0] = dd[0]; sder[tid][1] = dd[1]; sder[tid][2] = dd[2];
  }
  for (int i = tid; i < KK*NBP; i += 256) ((unsigned int*)lh)[i] = 0u;
  __syncthreads();
  float cxa[KK], cya[KK], sea[KK];
  #pragma unroll
  for (int k = 0; k < KK; ++k) {
    cxa[k] = sder[k][0]; cya[k] = sder[k][1]; sea[k] = sder[k][2];
  }
  const float inv = 1.f/511.f;
  const float* pbx = pred + (size_t)b*4*NPIX;
  const float* pby = pbx + NPIX;
  const float* pbd = pbx + 3*NPIX;
  const int*   ib  = inst + (size_t)b*NPIX;
  const int base = ch*2048 + g*128;        // group-private 128-px chunk
  float sloss = 0.f;
  #pragma unroll
  for (int it = 0; it < 2; ++it) {
    const int p = base + it*64 + l4*4;
    float4 px = *(const float4*)(pbx + p);
    float4 py = *(const float4*)(pby + p);
    int4   iv = *(const int4*)(ib + p);
    float4 dv = *(const float4*)(pbd + p);
    const float ym  = (float)(p >> 9) * inv;
    const float xm0 = (float)(p & (WW-1)) * inv;
    float pxa[4] = {px.x, px.y, px.z, px.w};
    float pya[4] = {py.x, py.y, py.z, py.w};
    int   ida[4] = {iv.x, iv.y, iv.z, iv.w};
    float sda[4] = {dv.x, dv.y, dv.z, dv.w};
    #pragma unroll
    for (int j = 0; j < 4; ++j) {
      float sex = fast_tanh(pxa[j]) + xm0 + (float)j*inv;
      float sey = fast_tanh(pya[j]) + ym;
      int id = ida[j];
      float down = 0.f;
      #pragma unroll
      for (int k = 0; k < KK; ++k) {
        float dx = sex - cxa[k], dy = sey - cya[k];
        float d = __expf(-sea[k]*(dx*dx + dy*dy));
        bool fg = (id == k+1);
        float u  = fg ? (1.f - d) : d;
        int bkt = (int)(u * (float)NB);
        bkt = bkt < (NB-1) ? bkt : (NB-1);
        atomicAdd(&lh[k][bkt], fg ? 0x10001u : 1u);
        down = fg ? d : down;
      }
      if (id >= 1) {
        float dsee = fast_sigmoid(sda[j]) - down;
        sloss = fmaf(dsee, dsee, sloss);
      }
    }
  }
  __syncthreads();
  #pragma unroll
  for (int k = 0; k < KK; ++k) {
    unsigned int* gh = hist + ((size_t)(b*KK + k)*CHV + ch)*NB;
    if (tid < NB) gh[tid] = lh[k][tid];
  }
  #pragma unroll
  for (int off = 32; off; off >>= 1) sloss += __shfl_down(sloss, off);
  if ((tid & 63) == 0) lsl[tid >> 6] = sloss;
  __syncthreads();
  if (tid == 0) partial_v[bid] = lsl[0] + lsl[1] + lsl[2] + lsl[3];
}

// ---------------- kernel 4: lovasz scan + FUSED final combine -------------
// grid 128 (one block per seg). Last-done block folds everything.
__global__ void __launch_bounds__(256) k_lovasz(
    const unsigned int* __restrict__ hist, const float* __restrict__ der,
    const float* __restrict__ partial_v, const float* __restrict__ partial_b,
    float* __restrict__ instl, unsigned int* __restrict__ done,
    float* __restrict__ out) {
  const int seg = blockIdx.x;
  const int tid = threadIdx.x;
  __shared__ float nbL[NB], fbL[NB];
  __shared__ unsigned int sOld;
  const float gts = der[seg*8 + 5];
  const unsigned int* h = hist + (size_t)seg*CHV*NB;
  if (tid < NB) {
    unsigned int nlo = 0, nhi = 0;
    #pragma unroll 8
    for (int c = 0; c < CHV; ++c) {
      unsigned int v = h[(size_t)c*NB + tid];
      nlo += v & 0xffffu; nhi += v >> 16;
    }
    nbL[tid] = (float)nlo; fbL[tid] = (float)nhi;
  }
  __syncthreads();
  // wave 0 scans; other waves wait at the barrier below
  if (tid < 64) {
    const int lane = tid;
    float lsum = 0.f;
    if (gts > 0.f) {
      float carryN = 0.f, carryF = 0.f;
      #pragma unroll
      for (int it = 0; it < NB/64; ++it) {
        int bkt = NB - 1 - (it*64 + lane);
        float nb = nbL[bkt], fb = fbL[bkt];
        float sn = nb, sf = fb;
        #pragma unroll
        for (int off = 1; off < 64; off <<= 1) {
          float tn = __shfl_up(sn, off);
          float tf = __shfl_up(sf, off);
          if (lane >= off) { sn += tn; sf += tf; }
        }
        float Nb = carryN + sn - nb;
        float Fb = carryF + sf - fb;
        if (nb > 0.f) {
          float e  = ((float)bkt + 0.5f) * (2.0f/(float)NB);
          float j0 = 1.f - (gts - Fb) / (gts + Nb - Fb);
          float N1 = Nb + nb, F1 = Fb + fb;
          float j1 = 1.f - (gts - F1) / (gts + N1 - F1);
          lsum += e * (j1 - j0);
        }
        carryN += __shfl(sn, 63);
        carryF += __shfl(sf, 63);
      }
      #pragma unroll
      for (int off = 32; off; off >>= 1) lsum += __shfl_down(lsum, off);
    }
    if (lane == 0) {
      instl[seg] = lsum;
      __threadfence();                    // publish instl device-wide
      sOld = atomicAdd(done, 1u);         // device-scope
    }
  }
  __syncthreads();
  if (sOld != BB*KK - 1) return;          // not the last block
  __threadfence();                        // acquire: see all instl stores
  // ---- final combine (all 256 threads) ----
  __shared__ float vtmp[256], btmp[256];
  {
    const int b8 = tid >> 5, j = tid & 31;
    float a = 0.f, c = 0.f;
    #pragma unroll
    for (int i = 0; i < 4; ++i) a += partial_v[(size_t)(j + 32*i)*8 + b8];
    #pragma unroll
    for (int i = 0; i < 8; ++i) c += partial_b[(size_t)(j + 32*i)*8 + b8];
    vtmp[tid] = a; btmp[tid] = c;
  }
  __syncthreads();
  float myv = 0.f;
  if (tid < BB) {
    int b = tid;
    float svl = 0.f, sbg = 0.f;
    #pragma unroll
    for (int j = 0; j < 32; ++j) { svl += vtmp[b*32 + j]; sbg += btmp[b*32 + j]; }
    float obj = 0.f, il = 0.f, vr = 0.f;
    for (int k = 0; k < KK; ++k) {
      int s2 = b*KK + k;
      float cnt = der[s2*8 + 5];
      if (cnt > 0.f) {
        obj += 1.f;
        il  += instl[s2];
        vr  += der[s2*8 + 6] / cnt;      // var/(N_SIGMA*safe), safe==cnt
      }
    }
    float so = fmaxf(obj, 1.f);
    myv = il/so + 10.f*vr/so + (sbg + svl)/(float)NPIX;
  }
  #pragma unroll
  for (int off = 4; off; off >>= 1) myv += __shfl_down(myv, off);
  if (tid == 0) out[0] = myv * (1.f/(float)BB);
}

extern "C" void kernel_launch(void* const* d_in, const int* in_sizes, int n_in,
                              void* d_out, int out_size, void* d_ws, size_t ws_size,
                              hipStream_t stream) {
  const float* pred = (const float*)d_in[0];
  const int*   inst = (const int*)d_in[1];
  const int*   lab  = (const int*)d_in[2];
  float* out = (float*)d_out;

  // ws layout (~13.3 MB of 256 MiB); all regions fully overwritten per call.
  float* der        = (float*)d_ws;                         // 128*8 f32
  float* instl      = (float*)((char*)d_ws + 4160);         // 128 f32
  unsigned int* done= (unsigned int*)((char*)d_ws + 4736);  // 1 u32
  float* partial_b  = (float*)((char*)d_ws + 8192);         // 2048 f32
  float* partial_v  = (float*)((char*)d_ws + 16384);        // 1024 f32
  float* partial_s  = (float*)((char*)d_ws + 24576);        // 8*80*256 f32
  unsigned int* hist= (unsigned int*)((char*)d_ws + 679936);// 128*128*192*4

  hipMemsetAsync(done, 0, 4, stream);
  k_sums  <<<BB*256, 256, 0, stream>>>(pred, inst, lab, partial_s, partial_b);
  k_reduce<<<BB*KK, 256, 0, stream>>>(partial_s, der);
  k_hist  <<<BB*CHV, 256, 0, stream>>>(pred, inst, der, hist, partial_v);
  k_lovasz<<<BB*KK, 256, 0, stream>>>(hist, der, partial_v, partial_b,
                                      instl, done, out);
}

// Round 21
// 61.169 us; speedup vs baseline: 2.7696x; 1.0705x over previous
//
#include <hip/hip_runtime.h>

#define HH 512
#define WW 512
#define NPIX (HH*WW)
#define KK 16
#define BB 8
#define NB 192   // lovasz error histogram buckets (%64==0)
#define NBP 200  // padded LDS hist row (bank stagger)
#define CHS 128  // pixel chunks per image in k_sums (2048 px each)
#define CHV 256  // pixel chunks per image in k_hist (1024 px each)

__device__ __forceinline__ float fast_rcp(float x){ return __builtin_amdgcn_rcpf(x); }
__device__ __forceinline__ float fast_tanh(float x){
  x = fminf(fmaxf(x, -15.f), 15.f);
  float t = __expf(2.f*x);
  return (t-1.f)*fast_rcp(t+1.f);
}
__device__ __forceinline__ float fast_sigmoid(float x){
  x = fminf(fmaxf(x, -30.f), 30.f);
  return fast_rcp(1.f+__expf(-x));
}

__device__ __forceinline__ float dpp_row_sum16(float v){
  v += __int_as_float(__builtin_amdgcn_update_dpp(0, __float_as_int(v), 0x111, 0xf, 0xf, true));
  v += __int_as_float(__builtin_amdgcn_update_dpp(0, __float_as_int(v), 0x112, 0xf, 0xf, true));
  v += __int_as_float(__builtin_amdgcn_update_dpp(0, __float_as_int(v), 0x114, 0xf, 0xf, true));
  v += __int_as_float(__builtin_amdgcn_update_dpp(0, __float_as_int(v), 0x118, 0xf, 0xf, true));
  return v;
}

// ---------------- kernel 1: mask sums (5 comps) + bg seed, 8 px/lane ------
// grid 1024: b = bid&7 (XCD-affine), ch = bid>>3 in [0,128); 2048 px/block.
// 8 px/lane halves the DPP butterfly volume (lanes x k x 20 ops).
__global__ void __launch_bounds__(256) k_sums(
    const float* __restrict__ pred, const int* __restrict__ inst,
    const int* __restrict__ lab, float* __restrict__ partial_s /*[B][80][128]*/,
    float* __restrict__ partial_b /*[1024]*/) {
  const int bid = blockIdx.x;
  const int b  = bid & 7;
  const int ch = bid >> 3;
  const int tid = threadIdx.x;
  const int wave = tid >> 6, lane = tid & 63;
  __shared__ float lred[KK][16][5];
  __shared__ float lbg[4];
  const float inv = 1.f/511.f;
  const float* ps = pred + (size_t)b*4*NPIX + 2*NPIX;
  const float* pd = ps + NPIX;
  const int*   ib = inst + (size_t)b*NPIX;
  const int*   lb = lab  + (size_t)b*NPIX;
  const int p = ch*2048 + tid*8;       // 8 px, same row (8 | 512)
  int4   iv0 = *(const int4*)(ib + p),     iv1 = *(const int4*)(ib + p + 4);
  int4   lv0 = *(const int4*)(lb + p),     lv1 = *(const int4*)(lb + p + 4);
  float4 sv0 = *(const float4*)(ps + p),   sv1 = *(const float4*)(ps + p + 4);
  float4 dv0 = *(const float4*)(pd + p),   dv1 = *(const float4*)(pd + p + 4);
  const float ym  = (float)(p >> 9) * inv;
  const float xm0 = (float)(p & (WW-1)) * inv;
  int   ida[8] = {iv0.x, iv0.y, iv0.z, iv0.w, iv1.x, iv1.y, iv1.z, iv1.w};
  int   laa[8] = {lv0.x, lv0.y, lv0.z, lv0.w, lv1.x, lv1.y, lv1.z, lv1.w};
  float sga[8] = {sv0.x, sv0.y, sv0.z, sv0.w, sv1.x, sv1.y, sv1.z, sv1.w};
  float sda[8] = {dv0.x, dv0.y, dv0.z, dv0.w, dv1.x, dv1.y, dv1.z, dv1.w};
  float xja[8], sg2[8];
  #pragma unroll
  for (int j = 0; j < 8; ++j) {
    xja[j] = xm0 + (float)j*inv;
    sg2[j] = sga[j]*sga[j];
  }

  float sbg = 0.f;
  #pragma unroll
  for (int j = 0; j < 8; ++j)
    if (laa[j] == 0) { float sd = fast_sigmoid(sda[j]); sbg += sd*sd; }
  #pragma unroll
  for (int off = 32; off; off >>= 1) sbg += __shfl_down(sbg, off);
  if (lane == 0) lbg[wave] = sbg;

  #pragma unroll
  for (int k = 0; k < KK; ++k) {
    float c = 0.f, sx = 0.f, ss = 0.f, sq = 0.f;
    #pragma unroll
    for (int j = 0; j < 8; ++j) {
      float m = (ida[j] == k+1) ? 1.f : 0.f;
      c  += m;
      sx = fmaf(m, xja[j], sx);
      ss = fmaf(m, sga[j], ss);
      sq = fmaf(m, sg2[j], sq);
    }
    float sy = c * ym;
    c  = dpp_row_sum16(c);
    sx = dpp_row_sum16(sx);
    sy = dpp_row_sum16(sy);
    ss = dpp_row_sum16(ss);
    sq = dpp_row_sum16(sq);
    if ((lane & 15) == 15) {
      int g = wave*4 + (lane >> 4);
      lred[k][g][0] = c;  lred[k][g][1] = sx; lred[k][g][2] = sy;
      lred[k][g][3] = ss; lred[k][g][4] = sq;
    }
  }
  __syncthreads();
  if (tid < KK) {
    #pragma unroll
    for (int comp = 0; comp < 5; ++comp) {
      float a = 0.f;
      #pragma unroll
      for (int g = 0; g < 16; ++g) a += lred[tid][g][comp];
      partial_s[((size_t)b*80 + tid*5 + comp)*CHS + ch] = a;
    }
  }
  if (tid == 64) partial_b[bid] = lbg[0] + lbg[1] + lbg[2] + lbg[3];
}

// ---------------- kernel 2: reduce partials -> der (grid 128, 1/seg) ------
// der[seg][8] = {cx, cy, sexp, act, sbar, cnt, var, pad}
__global__ void __launch_bounds__(128) k_reduce(
    const float* __restrict__ partial_s, float* __restrict__ der) {
  const int seg = blockIdx.x;           // b*16 + k
  const int b = seg >> 4, k = seg & 15;
  const int tid = threadIdx.x;          // 128 threads = CHS
  const int w = tid >> 6, l = tid & 63;
  __shared__ float red5[5][2];
  #pragma unroll
  for (int comp = 0; comp < 5; ++comp) {
    const float* row = partial_s + ((size_t)b*80 + k*5 + comp)*CHS;
    float a = row[tid];
    #pragma unroll
    for (int off = 32; off; off >>= 1) a += __shfl_down(a, off);
    if (l == 0) red5[comp][w] = a;
  }
  __syncthreads();
  if (tid == 0) {
    float cnt = red5[0][0]+red5[0][1];
    float sx  = red5[1][0]+red5[1][1];
    float sy  = red5[2][0]+red5[2][1];
    float ss  = red5[3][0]+red5[3][1];
    float sq  = red5[4][0]+red5[4][1];
    float safe = fmaxf(cnt, 1.f);
    float rs = fast_rcp(safe);
    float sb = ss*rs;
    float* dd = der + seg*8;
    dd[0] = sx*rs; dd[1] = sy*rs;
    dd[2] = __expf(10.f*sb);
    dd[3] = (cnt > 0.f) ? 1.f : 0.f;
    dd[4] = sb;
    dd[5] = cnt;
    dd[6] = sq - cnt*sb*sb;      // Σ(σ−s̄)² over mask
  }
}

// ---------------- kernel 3: unified 16-instance hist + fg seed loss -------
// grid 2048: b = bid&7, ch = bid>>3 in [0,256); 1024 px/block.
// NO forced waves-per-EU (R19 lesson: (256,8) caps VGPR at 32 -> spill);
// natural VGPR ~64-80 lets HW place 6-8 blocks/CU from the larger grid.
__global__ void __launch_bounds__(256, 4) k_hist(
    const float* __restrict__ pred, const int* __restrict__ inst,
    const float* __restrict__ der, unsigned int* __restrict__ hist,
    float* __restrict__ partial_v /*[2048]*/) {
  const int bid = blockIdx.x;
  const int b  = bid & 7;
  const int ch = bid >> 3;
  const int tid = threadIdx.x;
  const int g = tid >> 4, l4 = tid & 15;   // 16 groups x 16 lanes
  __shared__ unsigned int lh[KK][NBP];
  __shared__ float sder[KK][4];
  __shared__ float lsl[4];
  if (tid < KK) {
    const float* dd = der + (b*KK + tid)*8;
    sder[tid][0] = dd[0]; sder[tid][1] = dd[1]; sder[tid][2] = dd[2];
  }
  for (int i = tid; i < KK*NBP; i += 256) ((unsigned int*)lh)[i] = 0u;
  __syncthreads();
  float cxa[KK], cya[KK], sea[KK];
  #pragma unroll
  for (int k = 0; k < KK; ++k) {
    cxa[k] = sder[k][0]; cya[k] = sder[k][1]; sea[k] = sder[k][2];
  }
  const float inv = 1.f/511.f;
  const float* pbx = pred + (size_t)b*4*NPIX;
  const float* pby = pbx + NPIX;
  const float* pbd = pbx + 3*NPIX;
  const int*   ib  = inst + (size_t)b*NPIX;
  const int p = ch*1024 + g*64 + l4*4;     // group-private 64-px chunk
  float4 px = *(const float4*)(pbx + p);
  float4 py = *(const float4*)(pby + p);
  int4   iv = *(const int4*)(ib + p);
  float4 dv = *(const float4*)(pbd + p);
  const float ym  = (float)(p >> 9) * inv;
  const float xm0 = (float)(p & (WW-1)) * inv;
  float pxa[4] = {px.x, px.y, px.z, px.w};
  float pya[4] = {py.x, py.y, py.z, py.w};
  int   ida[4] = {iv.x, iv.y, iv.z, iv.w};
  float sda[4] = {dv.x, dv.y, dv.z, dv.w};
  float sloss = 0.f;
  #pragma unroll
  for (int j = 0; j < 4; ++j) {
    float sex = fast_tanh(pxa[j]) + xm0 + (float)j*inv;
    float sey = fast_tanh(pya[j]) + ym;
    int id = ida[j];
    float down = 0.f;
    #pragma unroll
    for (int k = 0; k < KK; ++k) {
      float dx = sex - cxa[k], dy = sey - cya[k];
      float d = __expf(-sea[k]*(dx*dx + dy*dy));
      bool fg = (id == k+1);
      float u  = fg ? (1.f - d) : d;
      int bkt = (int)(u * (float)NB);
      bkt = bkt < (NB-1) ? bkt : (NB-1);
      atomicAdd(&lh[k][bkt], fg ? 0x10001u : 1u);
      down = fg ? d : down;
    }
    if (id >= 1) {
      float dsee = fast_sigmoid(sda[j]) - down;
      sloss = fmaf(dsee, dsee, sloss);
    }
  }
  __syncthreads();
  #pragma unroll
  for (int k = 0; k < KK; ++k) {
    unsigned int* gh = hist + ((size_t)(b*KK + k)*CHV + ch)*NB;
    if (tid < NB) gh[tid] = lh[k][tid];
  }
  #pragma unroll
  for (int off = 32; off; off >>= 1) sloss += __shfl_down(sloss, off);
  if ((tid & 63) == 0) lsl[tid >> 6] = sloss;
  __syncthreads();
  if (tid == 0) partial_v[bid] = lsl[0] + lsl[1] + lsl[2] + lsl[3];
}

// ---------------- kernel 4: lovasz scan + FUSED final combine -------------
// grid 128 (one per seg). `done` is NEVER reset: (old & 127)==127 fires for
// exactly one block per call (any contiguous run of 128 increments contains
// exactly one value ==127 mod 128) -> no memset dispatch needed.
__global__ void __launch_bounds__(256) k_lovasz(
    const unsigned int* __restrict__ hist, const float* __restrict__ der,
    const float* __restrict__ partial_v, const float* __restrict__ partial_b,
    float* __restrict__ instl, unsigned int* __restrict__ done,
    float* __restrict__ out) {
  const int seg = blockIdx.x;
  const int tid = threadIdx.x;
  __shared__ float nbL[NB], fbL[NB];
  __shared__ unsigned int sOld;
  const float gts = der[seg*8 + 5];
  const unsigned int* h = hist + (size_t)seg*CHV*NB;
  if (tid < NB) {
    unsigned int nlo = 0, nhi = 0;
    #pragma unroll 8
    for (int c = 0; c < CHV; ++c) {
      unsigned int v = h[(size_t)c*NB + tid];
      nlo += v & 0xffffu; nhi += v >> 16;
    }
    nbL[tid] = (float)nlo; fbL[tid] = (float)nhi;
  }
  __syncthreads();
  if (tid < 64) {
    const int lane = tid;
    float lsum = 0.f;
    if (gts > 0.f) {
      float carryN = 0.f, carryF = 0.f;
      #pragma unroll
      for (int it = 0; it < NB/64; ++it) {
        int bkt = NB - 1 - (it*64 + lane);
        float nb = nbL[bkt], fb = fbL[bkt];
        float sn = nb, sf = fb;
        #pragma unroll
        for (int off = 1; off < 64; off <<= 1) {
          float tn = __shfl_up(sn, off);
          float tf = __shfl_up(sf, off);
          if (lane >= off) { sn += tn; sf += tf; }
        }
        float Nb = carryN + sn - nb;
        float Fb = carryF + sf - fb;
        if (nb > 0.f) {
          float e  = ((float)bkt + 0.5f) * (2.0f/(float)NB);
          float j0 = 1.f - (gts - Fb) / (gts + Nb - Fb);
          float N1 = Nb + nb, F1 = Fb + fb;
          float j1 = 1.f - (gts - F1) / (gts + N1 - F1);
          lsum += e * (j1 - j0);
        }
        carryN += __shfl(sn, 63);
        carryF += __shfl(sf, 63);
      }
      #pragma unroll
      for (int off = 32; off; off >>= 1) lsum += __shfl_down(lsum, off);
    }
    if (lane == 0) {
      instl[seg] = lsum;
      __threadfence();                    // publish instl device-wide
      sOld = atomicAdd(done, 1u);         // device-scope, never reset
    }
  }
  __syncthreads();
  if ((sOld & 127u) != 127u) return;      // not the last block this call
  __threadfence();                        // acquire: see all instl stores
  // ---- final combine (all 256 threads) ----
  __shared__ float vtmp[256], btmp[256];
  {
    const int b8 = tid >> 5, j = tid & 31;
    float a = 0.f, c = 0.f;
    #pragma unroll
    for (int i = 0; i < 8; ++i) a += partial_v[(size_t)(j + 32*i)*8 + b8];
    #pragma unroll
    for (int i = 0; i < 4; ++i) c += partial_b[(size_t)(j + 32*i)*8 + b8];
    vtmp[tid] = a; btmp[tid] = c;
  }
  __syncthreads();
  float myv = 0.f;
  if (tid < BB) {
    int b = tid;
    float svl = 0.f, sbg = 0.f;
    #pragma unroll
    for (int j = 0; j < 32; ++j) { svl += vtmp[b*32 + j]; sbg += btmp[b*32 + j]; }
    float obj = 0.f, il = 0.f, vr = 0.f;
    for (int k = 0; k < KK; ++k) {
      int s2 = b*KK + k;
      float cnt = der[s2*8 + 5];
      if (cnt > 0.f) {
        obj += 1.f;
        il  += instl[s2];
        vr  += der[s2*8 + 6] / cnt;      // var/(N_SIGMA*safe), safe==cnt
      }
    }
    float so = fmaxf(obj, 1.f);
    myv = il/so + 10.f*vr/so + (sbg + svl)/(float)NPIX;
  }
  #pragma unroll
  for (int off = 4; off; off >>= 1) myv += __shfl_down(myv, off);
  if (tid == 0) out[0] = myv * (1.f/(float)BB);
}

extern "C" void kernel_launch(void* const* d_in, const int* in_sizes, int n_in,
                              void* d_out, int out_size, void* d_ws, size_t ws_size,
                              hipStream_t stream) {
  const float* pred = (const float*)d_in[0];
  const int*   inst = (const int*)d_in[1];
  const int*   lab  = (const int*)d_in[2];
  float* out = (float*)d_out;

  // ws layout (~26 MB of 256 MiB); all consumed regions written every call.
  float* der        = (float*)d_ws;                         // 128*8 f32
  float* instl      = (float*)((char*)d_ws + 4160);         // 128 f32
  unsigned int* done= (unsigned int*)((char*)d_ws + 4736);  // 1 u32 (never reset)
  float* partial_b  = (float*)((char*)d_ws + 8192);         // 1024 f32
  float* partial_v  = (float*)((char*)d_ws + 16384);        // 2048 f32
  float* partial_s  = (float*)((char*)d_ws + 24576);        // 8*80*128 f32
  unsigned int* hist= (unsigned int*)((char*)d_ws + 679936);// 128*256*192*4

  k_sums  <<<BB*CHS, 256, 0, stream>>>(pred, inst, lab, partial_s, partial_b);
  k_reduce<<<BB*KK, 128, 0, stream>>>(partial_s, der);
  k_hist  <<<BB*CHV, 256, 0, stream>>>(pred, inst, der, hist, partial_v);
  k_lovasz<<<BB*KK, 256, 0, stream>>>(hist, der, partial_v, partial_b,
                                      instl, done, out);
}